// Round 6
// baseline (426.271 us; speedup 1.0000x reference)
//
#include <hip/hip_runtime.h>
#include <hip/hip_bf16.h>

typedef unsigned short u16;
typedef unsigned int u32;
typedef __attribute__((ext_vector_type(8))) short short8;
typedef __attribute__((ext_vector_type(4))) float floatx4;

#define NPIX 12544   // 112*112 = 49 * 256
#define KDIM 768     // channels = 24 * 32
#define EPSF 1e-8f
#define NCH 24       // K chunks of 32
#define NTILE 49     // 12544 / 256

// ---------------------------------------------------------------- async G->LDS
__device__ __forceinline__ void gload_lds16(const void* g, void* l) {
  __builtin_amdgcn_global_load_lds(
      (const __attribute__((address_space(1))) void*)g,
      (__attribute__((address_space(3))) void*)l, 16, 0, 0);
}

// sortable-uint encoding of float (monotone): max over enc == max over float
__device__ __forceinline__ u32 enc_f32(float f) {
  u32 u = __float_as_uint(f);
  return (u & 0x80000000u) ? ~u : (u | 0x80000000u);
}
__device__ __forceinline__ float dec_f32(u32 e) {
  u32 u = (e & 0x80000000u) ? (e & 0x7FFFFFFFu) : ~e;
  return __uint_as_float(u);
}

// ---------------------------------------------------------------- K1: column sum-of-squares partials
// grid (49, 8), block 256. pa/pb: [8][NPIX]
__global__ void colsumsq_kernel(const float* __restrict__ a, const float* __restrict__ b,
                                float* __restrict__ pa, float* __restrict__ pb) {
  int i = blockIdx.x * 256 + threadIdx.x;
  int c0 = blockIdx.y * 96;
  float sa = 0.f, sb = 0.f;
#pragma unroll 4
  for (int c = c0; c < c0 + 96; ++c) {
    float va = a[(size_t)c * NPIX + i];
    float vb = b[(size_t)c * NPIX + i];
    sa += va * va;
    sb += vb * vb;
  }
  pa[(size_t)blockIdx.y * NPIX + i] = sa;
  pb[(size_t)blockIdx.y * NPIX + i] = sb;
}

// ---------------------------------------------------------------- K2: 1/(sqrt(sum+eps)+eps) + zero the atomic-max buffer
// grid 49, block 256
__global__ void rnorm_kernel(const float* __restrict__ pa, const float* __restrict__ pb,
                             float* __restrict__ ra, float* __restrict__ rb,
                             u32* __restrict__ part) {
  int i = blockIdx.x * 256 + threadIdx.x;
  float sa = 0.f, sb = 0.f;
#pragma unroll
  for (int c = 0; c < 8; ++c) {
    sa += pa[(size_t)c * NPIX + i];
    sb += pb[(size_t)c * NPIX + i];
  }
  ra[i] = 1.f / (sqrtf(sa + EPSF) + EPSF);
  rb[i] = 1.f / (sqrtf(sb + EPSF) + EPSF);
  part[i] = 0u;  // encoded floor (< enc of any finite float)
}

// ---------------------------------------------------------------- K3: transpose + normalize + bf16 cast
// (C,N) f32 -> (N,C) bf16.  grid (392, 24, 2), block 256 (=32x8)
__global__ void transpose_kernel(const float* __restrict__ a, const float* __restrict__ b,
                                 const float* __restrict__ ra, const float* __restrict__ rb,
                                 u16* __restrict__ Ar, u16* __restrict__ Br) {
  const float* src = blockIdx.z ? b : a;
  const float* rn  = blockIdx.z ? rb : ra;
  u16* dst         = blockIdx.z ? Br : Ar;
  __shared__ float tile[32][33];
  int i0 = blockIdx.x * 32;
  int c0 = blockIdx.y * 32;
  int tx = threadIdx.x & 31;
  int ty = threadIdx.x >> 5;  // 0..7
#pragma unroll
  for (int d = 0; d < 4; ++d) {
    int c = c0 + ty + d * 8;
    tile[ty + d * 8][tx] = src[(size_t)c * NPIX + i0 + tx];
  }
  __syncthreads();
#pragma unroll
  for (int d = 0; d < 4; ++d) {
    int il = ty + d * 8;
    int gi = i0 + il;
    float v = tile[tx][il] * rn[gi];
    __hip_bfloat16 h = __float2bfloat16(v);
    dst[(size_t)gi * KDIM + c0 + tx] = *reinterpret_cast<u16*>(&h);
  }
}

// ---------------------------------------------------------------- K4: 256x256 tile, 8 waves,
// counted-vmcnt 4-slot ring + SOFTWARE-PIPELINED FRAG READS, 1 barrier/chunk.
// Round-6 change (round 5 = 305us/35% MfmaUtil): each MFMA cluster now consumes fragments
// read ONE PHASE EARLIER, so ds_read latency hides under the previous MFMA cluster instead
// of being drained by a pinned lgkmcnt(0) at the head of each cluster. Barriers cut 2->1
// per chunk (48->24). Compiler inserts fine-grained lgkm waits (m97-proven); no asm lgkm,
// no sched pinning inside the chunk body (m141: over-pinning regresses).
// Chunk c body (steady state; regs hold afc/bfc = chunk c's phi1 frags):
//   1. ds_read af2 (chunk c phi2 A-frags, slot c&3)
//   2. MFMA phi1 (afc,bfc) -> acc[0..3]            [af2 latency hides here]
//   3. s_waitcnt vmcnt(4)   <- counted: chunk c+2's 4 stages stay in flight
//   4. s_barrier            <- block-wide: slot c+1 landed; all waves past chunk c-1 phi2
//   5. STAGE4(c+3) -> slot (c-1)&3  [safe: by (4), every wave executed chunk c-1's phi2
//      MFMA, whose lgkm wait proves all slot-(c-1) reads completed]
//   6. ds_read afn/bfn (chunk c+1 phi1 frags, slot (c+1)&3)
//   7. MFMA phi2 (af2,bfc) -> acc[4..7]            [afn/bfn latency hides here]
// Tail: vmcnt(4)@c=21, vmcnt(0)@c=22, c=23 free-runs. Mid-loop never drains vmcnt to 0.
// LDS: 4 ring slots x (256x32 bf16) x {A,B} = 128 KiB, 1 block/CU.
// Swizzle (round-5 proven, 0 conflicts): LDS(row r, 16B-slot s) holds k-group (s-(r>>1))&3;
// global source pre-swizzled, LDS dest linear (both-sides-or-neither).
// Dispatch (round-3 proven, FETCH 485->161 MB): grid (8,7,49) x=XCD, y=col-in-chunk, z=row.
__global__ __launch_bounds__(512, 2) void gemm_max_kernel(const u16* __restrict__ Ar,
                                                          const u16* __restrict__ Br,
                                                          u32* __restrict__ part) {
  const int x = blockIdx.x;                 // XCD chunk (linear%8 == x)
  const int y = blockIdx.y;                 // col tile within chunk
  const int live = (x == 0) ? 7 : 6;
  if (y >= live) return;                    // dead padding block (exits before any barrier)
  const int ct = (x == 0) ? y : 7 + (x - 1) * 6 + y;
  const int rt = blockIdx.z;
  const int row_base = rt * 256;
  const int col_base = ct * 256;

  __shared__ alignas(16) u16 As[4 * 8192];  // 4 ring slots: [256 rows][4 slots][8 elems]
  __shared__ alignas(16) u16 Bs[4 * 8192];

  const int tid = threadIdx.x;
  const int lane = tid & 63;
  const int wid = tid >> 6;   // 0..7
  const int wm = wid >> 2;    // A half (0..1)
  const int wn = wid & 3;     // B quarter (0..3)
  const int l15 = lane & 15;
  const int quad = lane >> 4;

  // staging: thread covers rows (tid>>2) and (tid>>2)+128, 16B slot tid&3.
  const int srow = tid >> 2;                       // 0..127
  const int clog = ((tid & 3) - (srow >> 1)) & 3;  // logical 8-elem k-group (pre-swizzled)
  const u16* gAt = Ar + (size_t)(row_base + srow) * KDIM + clog * 8;
  const u16* gBt = Br + (size_t)(col_base + srow) * KDIM + clog * 8;
  u16* lA = &As[tid * 8];
  u16* lB = &Bs[tid * 8];

#define STAGE4(T)                                                              \
  do {                                                                         \
    gload_lds16(gAt + (T) * 32,              lA + (((T) & 3) << 13));          \
    gload_lds16(gAt + (T) * 32 + 128 * KDIM, lA + (((T) & 3) << 13) + 4096);   \
    gload_lds16(gBt + (T) * 32,              lB + (((T) & 3) << 13));          \
    gload_lds16(gBt + (T) * 32 + 128 * KDIM, lB + (((T) & 3) << 13) + 4096);   \
  } while (0)

  // frag element offsets within a slot: row R, k-quad quad -> R*32 + (((R>>1)+quad)&3)*8
  int aoff[8], boff[4];
#pragma unroll
  for (int mm = 0; mm < 8; ++mm) {
    int R = wm * 128 + mm * 16 + l15;
    aoff[mm] = R * 32 + ((((R >> 1) + quad) & 3) << 3);
  }
#pragma unroll
  for (int nf = 0; nf < 4; ++nf) {
    int Cc = wn * 64 + nf * 16 + l15;
    boff[nf] = Cc * 32 + ((((Cc >> 1) + quad) & 3) << 3);
  }

  floatx4 acc[8][4];
#pragma unroll
  for (int m = 0; m < 8; ++m)
#pragma unroll
    for (int n = 0; n < 4; ++n) acc[m][n] = (floatx4){0.f, 0.f, 0.f, 0.f};

  // prologue: stage chunks 0,1,2; wait chunk 0 landed (1,2 stay in flight); prime frags
  STAGE4(0); STAGE4(1); STAGE4(2);
  asm volatile("s_waitcnt vmcnt(8)" ::: "memory");
  __builtin_amdgcn_s_barrier();
  __builtin_amdgcn_sched_barrier(0);

  short8 afc[4], bfc[4];
#pragma unroll
  for (int mm = 0; mm < 4; ++mm) afc[mm] = *(const short8*)&As[aoff[mm]];
#pragma unroll
  for (int nf = 0; nf < 4; ++nf) bfc[nf] = *(const short8*)&Bs[boff[nf]];

#define CHUNK(C, DOSTG, VMSTR, DOWAIT, DONEXT)                                                \
  do {                                                                                        \
    const u16* pAs = &As[((C) & 3) << 13];                                                    \
    const u16* pBs = &Bs[((C) & 3) << 13];                                                    \
    const u16* pAn = &As[(((C) + 1) & 3) << 13];                                              \
    const u16* pBn = &Bs[(((C) + 1) & 3) << 13];                                              \
    short8 af2[4], afn[4], bfn[4];                                                            \
    _Pragma("unroll") for (int mm = 0; mm < 4; ++mm)                                          \
        af2[mm] = *(const short8*)&pAs[aoff[mm + 4]];                                         \
    __builtin_amdgcn_s_setprio(1);                                                            \
    _Pragma("unroll") for (int mm = 0; mm < 4; ++mm)                                          \
      _Pragma("unroll") for (int nf = 0; nf < 4; ++nf)                                        \
          acc[mm][nf] = __builtin_amdgcn_mfma_f32_16x16x32_bf16(afc[mm], bfc[nf],             \
                                                                acc[mm][nf], 0, 0, 0);        \
    __builtin_amdgcn_s_setprio(0);                                                            \
    if (DOWAIT) {                                                                             \
      asm volatile("s_waitcnt " VMSTR ::: "memory");                                          \
      __builtin_amdgcn_s_barrier();           /* slot C+1 landed; C-1 reads all done */       \
      __builtin_amdgcn_sched_barrier(0);      /* keep next reads/stage below the barrier */   \
    }                                                                                         \
    if (DOSTG) STAGE4((C) + 3);                                                               \
    if (DONEXT) {                                                                             \
      _Pragma("unroll") for (int mm = 0; mm < 4; ++mm)                                        \
          afn[mm] = *(const short8*)&pAn[aoff[mm]];                                           \
      _Pragma("unroll") for (int nf = 0; nf < 4; ++nf)                                        \
          bfn[nf] = *(const short8*)&pBn[boff[nf]];                                           \
    }                                                                                         \
    __builtin_amdgcn_s_setprio(1);                                                            \
    _Pragma("unroll") for (int mm = 0; mm < 4; ++mm)                                          \
      _Pragma("unroll") for (int nf = 0; nf < 4; ++nf)                                        \
          acc[mm + 4][nf] = __builtin_amdgcn_mfma_f32_16x16x32_bf16(af2[mm], bfc[nf],         \
                                                                    acc[mm + 4][nf], 0, 0, 0);\
    __builtin_amdgcn_s_setprio(0);                                                            \
    if (DONEXT) {                                                                             \
      _Pragma("unroll") for (int mm = 0; mm < 4; ++mm) afc[mm] = afn[mm];                     \
      _Pragma("unroll") for (int nf = 0; nf < 4; ++nf) bfc[nf] = bfn[nf];                     \
    }                                                                                         \
  } while (0)

  CHUNK(0,  1, "vmcnt(4)", 1, 1);  CHUNK(1,  1, "vmcnt(4)", 1, 1);
  CHUNK(2,  1, "vmcnt(4)", 1, 1);  CHUNK(3,  1, "vmcnt(4)", 1, 1);
  CHUNK(4,  1, "vmcnt(4)", 1, 1);  CHUNK(5,  1, "vmcnt(4)", 1, 1);
  CHUNK(6,  1, "vmcnt(4)", 1, 1);  CHUNK(7,  1, "vmcnt(4)", 1, 1);
  CHUNK(8,  1, "vmcnt(4)", 1, 1);  CHUNK(9,  1, "vmcnt(4)", 1, 1);
  CHUNK(10, 1, "vmcnt(4)", 1, 1);  CHUNK(11, 1, "vmcnt(4)", 1, 1);
  CHUNK(12, 1, "vmcnt(4)", 1, 1);  CHUNK(13, 1, "vmcnt(4)", 1, 1);
  CHUNK(14, 1, "vmcnt(4)", 1, 1);  CHUNK(15, 1, "vmcnt(4)", 1, 1);
  CHUNK(16, 1, "vmcnt(4)", 1, 1);  CHUNK(17, 1, "vmcnt(4)", 1, 1);
  CHUNK(18, 1, "vmcnt(4)", 1, 1);  CHUNK(19, 1, "vmcnt(4)", 1, 1);
  CHUNK(20, 1, "vmcnt(4)", 1, 1);
  CHUNK(21, 0, "vmcnt(4)", 1, 1);
  CHUNK(22, 0, "vmcnt(0)", 1, 1);
  CHUNK(23, 0, "vmcnt(0)", 0, 0);

#undef CHUNK
#undef STAGE4

  // epilogue: per-row max over the 256-col tile.
  // C frag layout: col = l15 (+n*16), row = quad*4 + rr (+m*16, +wm*128)
  // s_max overlays As slot 0 (4 KB): last slot-0 ds_read was chunk 20; every wave passed
  // barrier(22) before reaching here, which is ordered after all waves' chunk-21 bodies.
  float* s_max = reinterpret_cast<float*>(&As[0]);
#pragma unroll
  for (int m = 0; m < 8; ++m) {
#pragma unroll
    for (int rr = 0; rr < 4; ++rr) {
      float best = fmaxf(fmaxf(acc[m][0][rr], acc[m][1][rr]),
                         fmaxf(acc[m][2][rr], acc[m][3][rr]));
      best = fmaxf(best, __shfl_xor(best, 1));
      best = fmaxf(best, __shfl_xor(best, 2));
      best = fmaxf(best, __shfl_xor(best, 4));
      best = fmaxf(best, __shfl_xor(best, 8));
      if (l15 == 0)
        s_max[wn * 256 + wm * 128 + m * 16 + quad * 4 + rr] = best;  // unique writer per entry
    }
  }
  __syncthreads();
  if (tid < 256) {
    float mx = fmaxf(fmaxf(s_max[tid], s_max[256 + tid]),
                     fmaxf(s_max[512 + tid], s_max[768 + tid]));
    atomicMax(&part[row_base + tid], enc_f32(mx));
  }
}

// ---------------------------------------------------------------- K5: decode + loss
// single block, 1024 threads; output fp32 scalar
__global__ void finish_kernel(const u32* __restrict__ part, float* __restrict__ out) {
  float v = 0.f;
  for (int i = threadIdx.x; i < NPIX; i += 1024) {
    v += 1.0f - dec_f32(part[i]);
  }
#pragma unroll
  for (int off = 32; off > 0; off >>= 1) v += __shfl_down(v, off);
  __shared__ float red[16];
  int w = threadIdx.x >> 6;
  if ((threadIdx.x & 63) == 0) red[w] = v;
  __syncthreads();
  if (threadIdx.x == 0) {
    float s = 0.f;
#pragma unroll
    for (int k = 0; k < 16; ++k) s += red[k];
    out[0] = s * (1.0f / (float)NPIX);
  }
}

// ---------------------------------------------------------------- launcher
extern "C" void kernel_launch(void* const* d_in, const int* in_sizes, int n_in,
                              void* d_out, int out_size, void* d_ws, size_t ws_size,
                              hipStream_t stream) {
  const float* x = (const float*)d_in[0];
  const float* s = (const float*)d_in[1];
  char* ws = (char*)d_ws;
  // layout (bytes):
  float* pa   = (float*)(ws + 0);         //   401408
  float* pb   = (float*)(ws + 401408);    //   401408
  float* ra   = (float*)(ws + 802816);    //    50176
  float* rb   = (float*)(ws + 852992);    //    50176
  u32*   part = (u32*)  (ws + 903168);    //    50176 (encoded row maxima)
  u16*   Ar   = (u16*)  (ws + 953344);    // 19267584
  u16*   Br   = (u16*)  (ws + 20220928);  // 19267584  -> total 39488512 B

  colsumsq_kernel<<<dim3(49, 8), 256, 0, stream>>>(x, s, pa, pb);
  rnorm_kernel<<<49, 256, 0, stream>>>(pa, pb, ra, rb, part);
  transpose_kernel<<<dim3(392, 24, 2), 256, 0, stream>>>(x, s, ra, rb, Ar, Br);
  gemm_max_kernel<<<dim3(8, 7, 49), 512, 0, stream>>>(Ar, Br, part);
  finish_kernel<<<1, 1024, 0, stream>>>(part, (float*)d_out);
}

// Round 7
// 393.495 us; speedup vs baseline: 1.0833x; 1.0833x over previous
//
#include <hip/hip_runtime.h>
#include <hip/hip_bf16.h>

typedef unsigned short u16;
typedef unsigned int u32;
typedef __attribute__((ext_vector_type(8))) short short8;
typedef __attribute__((ext_vector_type(4))) float floatx4;

#define NPIX 12544   // 112*112 = 49 * 256
#define KDIM 768     // channels = 24 * 32
#define EPSF 1e-8f
#define NCH 24       // K chunks of 32
#define NTILE 49     // 12544 / 256

// ---------------------------------------------------------------- async G->LDS
__device__ __forceinline__ void gload_lds16(const void* g, void* l) {
  __builtin_amdgcn_global_load_lds(
      (const __attribute__((address_space(1))) void*)g,
      (__attribute__((address_space(3))) void*)l, 16, 0, 0);
}

// sortable-uint encoding of float (monotone): max over enc == max over float
__device__ __forceinline__ u32 enc_f32(float f) {
  u32 u = __float_as_uint(f);
  return (u & 0x80000000u) ? ~u : (u | 0x80000000u);
}
__device__ __forceinline__ float dec_f32(u32 e) {
  u32 u = (e & 0x80000000u) ? (e & 0x7FFFFFFFu) : ~e;
  return __uint_as_float(u);
}

// ---------------------------------------------------------------- K1: column sum-of-squares partials
// grid (49, 8), block 256. pa/pb: [8][NPIX]
__global__ void colsumsq_kernel(const float* __restrict__ a, const float* __restrict__ b,
                                float* __restrict__ pa, float* __restrict__ pb) {
  int i = blockIdx.x * 256 + threadIdx.x;
  int c0 = blockIdx.y * 96;
  float sa = 0.f, sb = 0.f;
#pragma unroll 4
  for (int c = c0; c < c0 + 96; ++c) {
    float va = a[(size_t)c * NPIX + i];
    float vb = b[(size_t)c * NPIX + i];
    sa += va * va;
    sb += vb * vb;
  }
  pa[(size_t)blockIdx.y * NPIX + i] = sa;
  pb[(size_t)blockIdx.y * NPIX + i] = sb;
}

// ---------------------------------------------------------------- K2: 1/(sqrt(sum+eps)+eps) + zero the atomic-max buffer
// grid 49, block 256
__global__ void rnorm_kernel(const float* __restrict__ pa, const float* __restrict__ pb,
                             float* __restrict__ ra, float* __restrict__ rb,
                             u32* __restrict__ part) {
  int i = blockIdx.x * 256 + threadIdx.x;
  float sa = 0.f, sb = 0.f;
#pragma unroll
  for (int c = 0; c < 8; ++c) {
    sa += pa[(size_t)c * NPIX + i];
    sb += pb[(size_t)c * NPIX + i];
  }
  ra[i] = 1.f / (sqrtf(sa + EPSF) + EPSF);
  rb[i] = 1.f / (sqrtf(sb + EPSF) + EPSF);
  part[i] = 0u;  // encoded floor (< enc of any finite float)
}

// ---------------------------------------------------------------- K3: transpose + normalize + bf16 cast
// (C,N) f32 -> (N,C) bf16.  grid (392, 24, 2), block 256 (=32x8)
__global__ void transpose_kernel(const float* __restrict__ a, const float* __restrict__ b,
                                 const float* __restrict__ ra, const float* __restrict__ rb,
                                 u16* __restrict__ Ar, u16* __restrict__ Br) {
  const float* src = blockIdx.z ? b : a;
  const float* rn  = blockIdx.z ? rb : ra;
  u16* dst         = blockIdx.z ? Br : Ar;
  __shared__ float tile[32][33];
  int i0 = blockIdx.x * 32;
  int c0 = blockIdx.y * 32;
  int tx = threadIdx.x & 31;
  int ty = threadIdx.x >> 5;  // 0..7
#pragma unroll
  for (int d = 0; d < 4; ++d) {
    int c = c0 + ty + d * 8;
    tile[ty + d * 8][tx] = src[(size_t)c * NPIX + i0 + tx];
  }
  __syncthreads();
#pragma unroll
  for (int d = 0; d < 4; ++d) {
    int il = ty + d * 8;
    int gi = i0 + il;
    float v = tile[tx][il] * rn[gi];
    __hip_bfloat16 h = __float2bfloat16(v);
    dst[(size_t)gi * KDIM + c0 + tx] = *reinterpret_cast<u16*>(&h);
  }
}

// ---------------------------------------------------------------- K4: 256x256 tile, 8 waves,
// counted-vmcnt 4-slot ring + SGB-ENFORCED DS_READ/MFMA ISSUE INTERLEAVE + balanced XCDs.
// Round-7 diagnosis: rounds 4/5/6 all = serial SUM of pipes (MFMA ~1240 + LDS ~1300 +
// VALU ~520 cyc/chunk = measured ~2900): after each barrier all 8 waves cluster their 12
// ds_reads BEFORE their MFMAs (scheduler latency heuristic), so LDS and MFMA phases
// alternate block-wide instead of overlapping. Fix A (T19): sched_group_barrier ladders
// pin the emitted interleave — R1: {1 DS_READ, 4 MFMA}x4 (af2 reads || phi1 MFMA),
// R2: {1 DS_READ, 2 MFMA}x8 (next-chunk frag reads || phi2 MFMA). Named counts match the
// region contents exactly; stage/VALU/copies float free. Fix B: XCD-balanced dispatch —
// grid (8,301): XCD k owns cols {k,k+8,...,k+40} (6 B-panels pinned, 2.3 MB) with rt slow
// and chip-synced (A shared; round-3's FETCH 161 MB preserved); col 48's 49 row-blocks are
// distributed round-robin at the tail. Per-XCD 300/301 blocks -> critical path 10 rounds
// (was 11 on XCD0 with grid (8,7,49): 343 blocks = +17% straggler).
// LDS: 4 ring slots x (256x32 bf16) x {A,B} = 128 KiB, 1 block/CU.
// Swizzle (round-5 proven, 0 conflicts): LDS(row r, 16B-slot s) holds k-group (s-(r>>1))&3;
// global source pre-swizzled, LDS dest linear (both-sides-or-neither).
// Ring safety/tail (round-5/6 proven): stage C+3 after barrier C (slot (C-1)&3 readers
// done via their phi2 lgkm waits); vmcnt(4) steady, 4/0/none at chunks 21/22/23.
__global__ __launch_bounds__(512, 2) void gemm_max_kernel(const u16* __restrict__ Ar,
                                                          const u16* __restrict__ Br,
                                                          u32* __restrict__ part) {
  const int xcd = blockIdx.x;   // linear%8 round-robins XCDs
  const int idx = blockIdx.y;   // 0..300 sequence within XCD
  int ct, rt;
  if (idx < 294) {
    ct = (idx % 6) * 8 + xcd;   // cols {xcd, 8+xcd, ..., 40+xcd} -> B pinned per XCD
    rt = idx / 6;               // rows advance slowly, chip-synchronized
  } else {
    int j = (idx - 294) * 8 + xcd;  // col 48 remainder: rows round-robin XCDs
    if (j >= NTILE) return;         // 7 dead blocks (xcd>0 at idx==300)
    ct = 48; rt = j;
  }
  const int row_base = rt * 256;
  const int col_base = ct * 256;

  __shared__ alignas(16) u16 As[4 * 8192];  // 4 ring slots: [256 rows][4 slots][8 elems]
  __shared__ alignas(16) u16 Bs[4 * 8192];

  const int tid = threadIdx.x;
  const int lane = tid & 63;
  const int wid = tid >> 6;   // 0..7
  const int wm = wid >> 2;    // A half (0..1)
  const int wn = wid & 3;     // B quarter (0..3)
  const int l15 = lane & 15;
  const int quad = lane >> 4;

  // staging: thread covers rows (tid>>2) and (tid>>2)+128, 16B slot tid&3.
  const int srow = tid >> 2;                       // 0..127
  const int clog = ((tid & 3) - (srow >> 1)) & 3;  // logical 8-elem k-group (pre-swizzled)
  const u16* gAt = Ar + (size_t)(row_base + srow) * KDIM + clog * 8;
  const u16* gBt = Br + (size_t)(col_base + srow) * KDIM + clog * 8;
  u16* lA = &As[tid * 8];
  u16* lB = &Bs[tid * 8];

#define STAGE4(T)                                                              \
  do {                                                                         \
    gload_lds16(gAt + (T) * 32,              lA + (((T) & 3) << 13));          \
    gload_lds16(gAt + (T) * 32 + 128 * KDIM, lA + (((T) & 3) << 13) + 4096);   \
    gload_lds16(gBt + (T) * 32,              lB + (((T) & 3) << 13));          \
    gload_lds16(gBt + (T) * 32 + 128 * KDIM, lB + (((T) & 3) << 13) + 4096);   \
  } while (0)

  // frag element offsets within a slot: row R, k-quad quad -> R*32 + (((R>>1)+quad)&3)*8
  int aoff[8], boff[4];
#pragma unroll
  for (int mm = 0; mm < 8; ++mm) {
    int R = wm * 128 + mm * 16 + l15;
    aoff[mm] = R * 32 + ((((R >> 1) + quad) & 3) << 3);
  }
#pragma unroll
  for (int nf = 0; nf < 4; ++nf) {
    int Cc = wn * 64 + nf * 16 + l15;
    boff[nf] = Cc * 32 + ((((Cc >> 1) + quad) & 3) << 3);
  }

  floatx4 acc[8][4];
#pragma unroll
  for (int m = 0; m < 8; ++m)
#pragma unroll
    for (int n = 0; n < 4; ++n) acc[m][n] = (floatx4){0.f, 0.f, 0.f, 0.f};

  // prologue: stage chunks 0,1,2; wait chunk 0 landed (1,2 stay in flight); prime frags
  STAGE4(0); STAGE4(1); STAGE4(2);
  asm volatile("s_waitcnt vmcnt(8)" ::: "memory");
  __builtin_amdgcn_s_barrier();
  __builtin_amdgcn_sched_barrier(0);

  short8 afc[4], bfc[4];
#pragma unroll
  for (int mm = 0; mm < 4; ++mm) afc[mm] = *(const short8*)&As[aoff[mm]];
#pragma unroll
  for (int nf = 0; nf < 4; ++nf) bfc[nf] = *(const short8*)&Bs[boff[nf]];

#define CHUNK(C, DOSTG, VMSTR, DOWAIT, DONEXT)                                                \
  do {                                                                                        \
    const u16* pAs = &As[((C) & 3) << 13];                                                    \
    const u16* pBs = &Bs[((C) & 3) << 13];                                                    \
    const u16* pAn = &As[(((C) + 1) & 3) << 13];                                              \
    const u16* pBn = &Bs[(((C) + 1) & 3) << 13];                                              \
    short8 af2[4], afn[4], bfn[4];                                                            \
    /* R1: af2 reads (slot C) || phi1 MFMA (afc,bfc ready in regs) */                         \
    _Pragma("unroll") for (int mm = 0; mm < 4; ++mm)                                          \
        af2[mm] = *(const short8*)&pAs[aoff[mm + 4]];                                         \
    _Pragma("unroll") for (int mm = 0; mm < 4; ++mm)                                          \
      _Pragma("unroll") for (int nf = 0; nf < 4; ++nf)                                        \
          acc[mm][nf] = __builtin_amdgcn_mfma_f32_16x16x32_bf16(afc[mm], bfc[nf],             \
                                                                acc[mm][nf], 0, 0, 0);        \
    _Pragma("unroll") for (int g = 0; g < 4; ++g) {                                           \
      __builtin_amdgcn_sched_group_barrier(0x100, 1, 0); /* 1 ds_read      */                 \
      __builtin_amdgcn_sched_group_barrier(0x008, 4, 0); /* 4 mfma         */                 \
    }                                                                                         \
    if (DOWAIT) {                                                                             \
      asm volatile("s_waitcnt " VMSTR ::: "memory");                                          \
      __builtin_amdgcn_s_barrier();           /* slot C+1 landed; C-1 reads all done */       \
      __builtin_amdgcn_sched_barrier(0);                                                      \
    }                                                                                         \
    if (DOSTG) STAGE4((C) + 3);                                                               \
    /* R2: next-chunk frag reads (slot C+1) || phi2 MFMA (af2 from R1, lgkm-covered) */       \
    if (DONEXT) {                                                                             \
      _Pragma("unroll") for (int mm = 0; mm < 4; ++mm)                                        \
          afn[mm] = *(const short8*)&pAn[aoff[mm]];                                           \
      _Pragma("unroll") for (int nf = 0; nf < 4; ++nf)                                        \
          bfn[nf] = *(const short8*)&pBn[boff[nf]];                                           \
    }                                                                                         \
    _Pragma("unroll") for (int mm = 0; mm < 4; ++mm)                                          \
      _Pragma("unroll") for (int nf = 0; nf < 4; ++nf)                                        \
          acc[mm + 4][nf] = __builtin_amdgcn_mfma_f32_16x16x32_bf16(af2[mm], bfc[nf],         \
                                                                    acc[mm + 4][nf], 0, 0, 0);\
    if (DONEXT) {                                                                             \
      _Pragma("unroll") for (int g = 0; g < 8; ++g) {                                         \
        __builtin_amdgcn_sched_group_barrier(0x100, 1, 0); /* 1 ds_read    */                 \
        __builtin_amdgcn_sched_group_barrier(0x008, 2, 0); /* 2 mfma       */                 \
      }                                                                                       \
      _Pragma("unroll") for (int mm = 0; mm < 4; ++mm) afc[mm] = afn[mm];                     \
      _Pragma("unroll") for (int nf = 0; nf < 4; ++nf) bfc[nf] = bfn[nf];                     \
    }                                                                                         \
  } while (0)

  CHUNK(0,  1, "vmcnt(4)", 1, 1);  CHUNK(1,  1, "vmcnt(4)", 1, 1);
  CHUNK(2,  1, "vmcnt(4)", 1, 1);  CHUNK(3,  1, "vmcnt(4)", 1, 1);
  CHUNK(4,  1, "vmcnt(4)", 1, 1);  CHUNK(5,  1, "vmcnt(4)", 1, 1);
  CHUNK(6,  1, "vmcnt(4)", 1, 1);  CHUNK(7,  1, "vmcnt(4)", 1, 1);
  CHUNK(8,  1, "vmcnt(4)", 1, 1);  CHUNK(9,  1, "vmcnt(4)", 1, 1);
  CHUNK(10, 1, "vmcnt(4)", 1, 1);  CHUNK(11, 1, "vmcnt(4)", 1, 1);
  CHUNK(12, 1, "vmcnt(4)", 1, 1);  CHUNK(13, 1, "vmcnt(4)", 1, 1);
  CHUNK(14, 1, "vmcnt(4)", 1, 1);  CHUNK(15, 1, "vmcnt(4)", 1, 1);
  CHUNK(16, 1, "vmcnt(4)", 1, 1);  CHUNK(17, 1, "vmcnt(4)", 1, 1);
  CHUNK(18, 1, "vmcnt(4)", 1, 1);  CHUNK(19, 1, "vmcnt(4)", 1, 1);
  CHUNK(20, 1, "vmcnt(4)", 1, 1);
  CHUNK(21, 0, "vmcnt(4)", 1, 1);
  CHUNK(22, 0, "vmcnt(0)", 1, 1);
  CHUNK(23, 0, "vmcnt(0)", 0, 0);

#undef CHUNK
#undef STAGE4

  // epilogue: per-row max over the 256-col tile.
  // C frag layout: col = l15 (+n*16), row = quad*4 + rr (+m*16, +wm*128)
  // s_max overlays As slot 0: last slot-0 reads (ch19-R2/ch20-R1) are lgkm-drained by each
  // wave's own ch20 MFMAs; all waves passed barrier(22) before any epilogue write.
  float* s_max = reinterpret_cast<float*>(&As[0]);
#pragma unroll
  for (int m = 0; m < 8; ++m) {
#pragma unroll
    for (int rr = 0; rr < 4; ++rr) {
      float best = fmaxf(fmaxf(acc[m][0][rr], acc[m][1][rr]),
                         fmaxf(acc[m][2][rr], acc[m][3][rr]));
      best = fmaxf(best, __shfl_xor(best, 1));
      best = fmaxf(best, __shfl_xor(best, 2));
      best = fmaxf(best, __shfl_xor(best, 4));
      best = fmaxf(best, __shfl_xor(best, 8));
      if (l15 == 0)
        s_max[wn * 256 + wm * 128 + m * 16 + quad * 4 + rr] = best;  // unique writer per entry
    }
  }
  __syncthreads();
  if (tid < 256) {
    float mx = fmaxf(fmaxf(s_max[tid], s_max[256 + tid]),
                     fmaxf(s_max[512 + tid], s_max[768 + tid]));
    atomicMax(&part[row_base + tid], enc_f32(mx));
  }
}

// ---------------------------------------------------------------- K5: decode + loss
// single block, 1024 threads; output fp32 scalar
__global__ void finish_kernel(const u32* __restrict__ part, float* __restrict__ out) {
  float v = 0.f;
  for (int i = threadIdx.x; i < NPIX; i += 1024) {
    v += 1.0f - dec_f32(part[i]);
  }
#pragma unroll
  for (int off = 32; off > 0; off >>= 1) v += __shfl_down(v, off);
  __shared__ float red[16];
  int w = threadIdx.x >> 6;
  if ((threadIdx.x & 63) == 0) red[w] = v;
  __syncthreads();
  if (threadIdx.x == 0) {
    float s = 0.f;
#pragma unroll
    for (int k = 0; k < 16; ++k) s += red[k];
    out[0] = s * (1.0f / (float)NPIX);
  }
}

// ---------------------------------------------------------------- launcher
extern "C" void kernel_launch(void* const* d_in, const int* in_sizes, int n_in,
                              void* d_out, int out_size, void* d_ws, size_t ws_size,
                              hipStream_t stream) {
  const float* x = (const float*)d_in[0];
  const float* s = (const float*)d_in[1];
  char* ws = (char*)d_ws;
  // layout (bytes):
  float* pa   = (float*)(ws + 0);         //   401408
  float* pb   = (float*)(ws + 401408);    //   401408
  float* ra   = (float*)(ws + 802816);    //    50176
  float* rb   = (float*)(ws + 852992);    //    50176
  u32*   part = (u32*)  (ws + 903168);    //    50176 (encoded row maxima)
  u16*   Ar   = (u16*)  (ws + 953344);    // 19267584
  u16*   Br   = (u16*)  (ws + 20220928);  // 19267584  -> total 39488512 B

  colsumsq_kernel<<<dim3(49, 8), 256, 0, stream>>>(x, s, pa, pb);
  rnorm_kernel<<<49, 256, 0, stream>>>(pa, pb, ra, rb, part);
  transpose_kernel<<<dim3(392, 24, 2), 256, 0, stream>>>(x, s, ra, rb, Ar, Br);
  gemm_max_kernel<<<dim3(8, 301), 512, 0, stream>>>(Ar, Br, part);
  finish_kernel<<<1, 1024, 0, stream>>>(part, (float*)d_out);
}